// Round 8
// baseline (612.710 us; speedup 1.0000x reference)
//
#include <hip/hip_runtime.h>

#define NBRS 200
#define BATCH 2048
#define FEW 5
#define DMODEL 256
#define DINNER 512
#define LHID 512
#define GDIM 2048   // 4*LHID
#define EDIM 128
#define LNEPS 1e-3f

typedef unsigned short ushort_t;
typedef short s16x8 __attribute__((ext_vector_type(8)));
typedef float f32x4 __attribute__((ext_vector_type(4)));

__device__ __forceinline__ float sigmoidf_(float x) { return 1.f / (1.f + expf(-x)); }

__device__ __forceinline__ ushort_t f2bf(float f) {  // RNE float->bf16
    union { float f; unsigned u; } v; v.f = f;
    unsigned u = v.u;
    return (ushort_t)((u + 0x7FFFu + ((u >> 16) & 1u)) >> 16);
}
__device__ __forceinline__ float bf2f(ushort_t h) {
    union { unsigned u; float f; } v; v.u = (unsigned)h << 16; return v.f;
}

// ---------------------------------------------------------------------------
// Fused gather + sum + GCN matvec + tanh for all 4 connection tables.
// Query blocks also emit qn3 = [hi, hi, lo] bf16x3 panel (K'=768).
// ---------------------------------------------------------------------------
__global__ __launch_bounds__(256) void nbr_gcn(
    const int* __restrict__ qlc, const float* __restrict__ qld,
    const int* __restrict__ qrc, const float* __restrict__ qrd,
    const int* __restrict__ slc, const float* __restrict__ sld,
    const int* __restrict__ src_, const float* __restrict__ srd,
    const float* __restrict__ emb, const float* __restrict__ WT,
    const float* __restrict__ bias, float* __restrict__ qn, float* __restrict__ sn,
    ushort_t* __restrict__ qn3) {
    __shared__ int idx[NBRS * 2];
    __shared__ float red[4][256];
    __shared__ float sS[256];
    __shared__ float part[256];

    int b = blockIdx.x;
    const int* conn; const float* deg; float* outp; int off, row; bool isq;
    if (b < 2048)      { conn = qlc;  deg = qld; outp = qn; off = 0;   row = b;        isq = true; }
    else if (b < 4096) { conn = qrc;  deg = qrd; outp = qn; off = 128; row = b - 2048; isq = true; }
    else if (b < 4101) { conn = slc;  deg = sld; outp = sn; off = 0;   row = b - 4096; isq = false; }
    else               { conn = src_; deg = srd; outp = sn; off = 128; row = b - 4101; isq = false; }

    int t = threadIdx.x;
    for (int i = t; i < NBRS * 2; i += 256) idx[i] = conn[row * NBRS * 2 + i];
    __syncthreads();

    int g = t >> 6;
    int r = t & 63;
    int sel = r >> 5;
    int d4 = r & 31;
    float4 acc = make_float4(0.f, 0.f, 0.f, 0.f);
#pragma unroll 5
    for (int k = g; k < NBRS; k += 4) {
        int e = idx[k * 2 + sel];
        float4 v = *(const float4*)(emb + (size_t)e * EDIM + d4 * 4);
        acc.x += v.x; acc.y += v.y; acc.z += v.z; acc.w += v.w;
    }
    *(float4*)&red[g][sel * 128 + d4 * 4] = acc;
    __syncthreads();
    sS[t] = red[0][t] + red[1][t] + red[2][t] + red[3][t];
    __syncthreads();

    int d = t & 127;
    int half = t >> 7;
    float a = 0.f;
    const float* w = WT + (size_t)(half * 128) * 128 + d;
    const float* s = sS + half * 128;
#pragma unroll 8
    for (int c = 0; c < 128; ++c) a = fmaf(s[c], w[(size_t)c * 128], a);
    part[t] = a;
    __syncthreads();
    if (t < 128) {
        float v = (part[t] + part[t + 128] + 200.f * bias[t]) / deg[row];
        float y = tanhf(v);
        outp[(size_t)row * 256 + off + t] = y;
        if (isq) {
            ushort_t hi = f2bf(y);
            ushort_t lo = f2bf(y - bf2f(hi));
            ushort_t* p = qn3 + (size_t)row * 768;
            p[off + t] = hi; p[256 + off + t] = hi; p[512 + off + t] = lo;
        }
    }
}

// gcn_w (128,256) -> gcn_wT (256,128)
__global__ void transpose_gcnw(const float* __restrict__ W, float* __restrict__ WT) {
    int i = blockIdx.x * 256 + threadIdx.x;
    int d = i >> 8, c = i & 255;
    WT[c * 128 + d] = W[i];
}

// Weight fp32 (N rows, K cols used, row stride src_ld) -> N x 3K bf16 [hi, lo, hi]
__global__ __launch_bounds__(256) void convert_w(const float* __restrict__ W, int src_ld,
                                                 ushort_t* __restrict__ W3, int K, int total) {
    int i = blockIdx.x * 256 + threadIdx.x;
    if (i >= total) return;
    int n = i / K, k = i % K;
    float w = W[(size_t)n * src_ld + k];
    ushort_t hi = f2bf(w);
    ushort_t lo = f2bf(w - bf2f(hi));
    ushort_t* p = W3 + (size_t)n * 3 * K;
    p[k] = hi; p[K + k] = lo; p[2 * K + k] = hi;
}

// ---------------------------------------------------------------------------
// bf16 MFMA NT GEMM over the x3-split panels: C = A·B^T (fp32 accum).
// A: M x K' bf16 row-major, B: N x K' bf16 row-major. M%64==0, N%128==0, K'%64==0.
// Tile 64x128, BK=64, 256 thr = 4 waves (2M x 2N), wave = 32x64 = 2x4 frags 16x16.
// LDS XOR-swizzle (slot ^= row&7) -> conflict-free ds_read_b128 (G4).
// OUT3: write bf16x3 activation panel [hi,hi,lo] (ldc3=3*Nfull) instead of fp32.
// ---------------------------------------------------------------------------
template <int RELU, int BIAS, int ADD, int OUT3>
__global__ __launch_bounds__(256) void gemm_bf3(
    const ushort_t* __restrict__ A, int lda,
    const ushort_t* __restrict__ B, int ldb,
    float* __restrict__ Cf, int ldc,
    ushort_t* __restrict__ C3, int Nfull,
    const float* __restrict__ bias,
    const float* __restrict__ addm, int ldadd, int K) {
    __shared__ ushort_t As[64 * 64];
    __shared__ ushort_t Bs[128 * 64];
    const int tid = threadIdx.x;
    const int m0 = blockIdx.y * 64;
    const int n0 = blockIdx.x * 128;
    const int w = tid >> 6, lane = tid & 63;
    const int wm = w >> 1, wn = w & 1;
    const int fr = lane & 15, fq = lane >> 4;

    f32x4 zero = {0.f, 0.f, 0.f, 0.f};
    f32x4 acc[2][4];
#pragma unroll
    for (int i = 0; i < 2; i++)
#pragma unroll
        for (int j = 0; j < 4; j++) acc[i][j] = zero;

    uint4 ra[2], rb[4];
    auto gload = [&](int k0) {
#pragma unroll
        for (int l = 0; l < 2; ++l) {
            int c = tid + l * 256, rw = c >> 3, sl = c & 7;
            ra[l] = *(const uint4*)(A + (size_t)(m0 + rw) * lda + k0 + sl * 8);
        }
#pragma unroll
        for (int l = 0; l < 4; ++l) {
            int c = tid + l * 256, rw = c >> 3, sl = c & 7;
            rb[l] = *(const uint4*)(B + (size_t)(n0 + rw) * ldb + k0 + sl * 8);
        }
    };
    auto sstore = [&]() {
#pragma unroll
        for (int l = 0; l < 2; ++l) {
            int c = tid + l * 256, rw = c >> 3, sl = c & 7;
            *(uint4*)&As[rw * 64 + ((sl ^ (rw & 7)) << 3)] = ra[l];
        }
#pragma unroll
        for (int l = 0; l < 4; ++l) {
            int c = tid + l * 256, rw = c >> 3, sl = c & 7;
            *(uint4*)&Bs[rw * 64 + ((sl ^ (rw & 7)) << 3)] = rb[l];
        }
    };

    const int nt = K / 64;
    gload(0);
    for (int kt = 0; kt < nt; ++kt) {
        if (kt) __syncthreads();
        sstore();
        __syncthreads();
        if (kt + 1 < nt) gload((kt + 1) * 64);
#pragma unroll
        for (int ks = 0; ks < 2; ++ks) {
            s16x8 av[2], bv[4];
#pragma unroll
            for (int fm = 0; fm < 2; ++fm) {
                int rw = wm * 32 + fm * 16 + fr;
                int s16 = ks * 4 + fq;
                av[fm] = *(const s16x8*)&As[rw * 64 + ((s16 ^ (rw & 7)) << 3)];
            }
#pragma unroll
            for (int fn = 0; fn < 4; ++fn) {
                int rw = wn * 64 + fn * 16 + fr;
                int s16 = ks * 4 + fq;
                bv[fn] = *(const s16x8*)&Bs[rw * 64 + ((s16 ^ (rw & 7)) << 3)];
            }
#pragma unroll
            for (int fm = 0; fm < 2; ++fm)
#pragma unroll
                for (int fn = 0; fn < 4; ++fn)
                    acc[fm][fn] = __builtin_amdgcn_mfma_f32_16x16x32_bf16(
                        av[fm], bv[fn], acc[fm][fn], 0, 0, 0);
        }
    }

#pragma unroll
    for (int fm = 0; fm < 2; ++fm)
#pragma unroll
        for (int fn = 0; fn < 4; ++fn)
#pragma unroll
            for (int r = 0; r < 4; ++r) {
                int gm = m0 + wm * 32 + fm * 16 + fq * 4 + r;
                int gn = n0 + wn * 64 + fn * 16 + fr;
                float v = acc[fm][fn][r];
                if (BIAS) v += bias[gn];
                if (ADD) v += addm[(size_t)gm * ldadd + gn];
                if (RELU) v = fmaxf(v, 0.f);
                if (OUT3) {
                    ushort_t hi = f2bf(v);
                    ushort_t lo = f2bf(v - bf2f(hi));
                    ushort_t* p = C3 + (size_t)gm * (3 * Nfull);
                    p[gn] = hi; p[gn + Nfull] = hi; p[gn + 2 * Nfull] = lo;
                } else {
                    Cf[(size_t)gm * ldc + gn] = v;
                }
            }
}

// Tiny-M GEMM (M=5 support rows): one thread per output. fp32.
template <int RELU, int BIAS, int ADD>
__global__ __launch_bounds__(256) void small_nt(const float* __restrict__ A, int lda,
                                                const float* __restrict__ B, int ldb,
                                                float* __restrict__ C, int ldc,
                                                const float* __restrict__ bias,
                                                const float* __restrict__ addm, int ldadd,
                                                int M, int N, int K) {
    int o = blockIdx.x * 256 + threadIdx.x;
    if (o >= M * N) return;
    int m = o / N, n = o % N;
    const float4* a4 = (const float4*)(A + (size_t)m * lda);
    const float4* b4 = (const float4*)(B + (size_t)n * ldb);
    float s = 0.f;
#pragma unroll 8
    for (int k = 0; k < K / 4; ++k) {
        float4 x = a4[k], y = b4[k];
        s += x.x * y.x + x.y * y.y + x.z * y.z + x.w * y.w;
    }
    if (BIAS) s += bias[n];
    if (ADD) s += addm[(size_t)m * ldadd + n];
    if (RELU) s = fmaxf(s, 0.f);
    C[(size_t)m * ldc + n] = s;
}

// LayerNorm (ddof=1), one wave per 256-elem row; optional bf16x3 panel out.
__global__ __launch_bounds__(256) void ln_kernel(const float* __restrict__ X,
                                                 const float* __restrict__ la,
                                                 const float* __restrict__ lb,
                                                 float* __restrict__ Y,
                                                 ushort_t* __restrict__ Y3, int n) {
    int row = blockIdx.x * 4 + (threadIdx.x >> 6);
    int lane = threadIdx.x & 63;
    if (row >= n) return;
    float4 x = *(const float4*)(X + (size_t)row * 256 + lane * 4);
    float s = x.x + x.y + x.z + x.w;
#pragma unroll
    for (int o = 32; o; o >>= 1) s += __shfl_xor(s, o);
    float mu = s * (1.f / 256.f);
    float d0 = x.x - mu, d1 = x.y - mu, d2 = x.z - mu, d3 = x.w - mu;
    float q = d0 * d0 + d1 * d1 + d2 * d2 + d3 * d3;
#pragma unroll
    for (int o = 32; o; o >>= 1) q += __shfl_xor(q, o);
    float sigma = sqrtf(q * (1.f / 255.f));
    float inv = 1.f / (sigma + LNEPS);
    float4 a = *(const float4*)(la + lane * 4);
    float4 b = *(const float4*)(lb + lane * 4);
    float4 y = make_float4(d0 * inv * a.x + b.x, d1 * inv * a.y + b.y,
                           d2 * inv * a.z + b.z, d3 * inv * a.w + b.w);
    *(float4*)(Y + (size_t)row * 256 + lane * 4) = y;
    if (Y3) {
        ushort_t* p = Y3 + (size_t)row * 768;
        float vv[4] = {y.x, y.y, y.z, y.w};
#pragma unroll
        for (int c = 0; c < 4; ++c) {
            int col = lane * 4 + c;
            ushort_t hi = f2bf(vv[c]);
            p[col] = hi; p[col + 256] = hi; p[col + 512] = f2bf(vv[c] - bf2f(hi));
        }
    }
}

__global__ void mean5(const float* __restrict__ sg, float* __restrict__ s) {
    int d = threadIdx.x;
    float v = 0.f;
#pragma unroll
    for (int r = 0; r < FEW; r++) v += sg[r * 256 + d];
    s[d] = v * (1.f / FEW);
}

__global__ __launch_bounds__(256) void svec_bsum(const float* __restrict__ s,
                                                 const float* __restrict__ w_hh,
                                                 const float* __restrict__ b_ih,
                                                 const float* __restrict__ b_hh,
                                                 float* __restrict__ svec,
                                                 float* __restrict__ bsum) {
    int j = blockIdx.x * 4 + (threadIdx.x >> 6);
    int lane = threadIdx.x & 63;
    const float* w = w_hh + (size_t)j * LHID + 256;
    float4 v = ((const float4*)w)[lane];
    float4 sv = ((const float4*)s)[lane];
    float p = v.x * sv.x + v.y * sv.y + v.z * sv.z + v.w * sv.w;
#pragma unroll
    for (int o = 32; o; o >>= 1) p += __shfl_down(p, o);
    if (lane == 0) {
        svec[j] = p;
        bsum[j] = b_ih[j] + b_hh[j];
    }
}

// LSTM gates; H fp32 + Hst3 bf16x3 panel for the next step GEMM.
template <int FIRST>
__global__ __launch_bounds__(256) void gates_kernel(const float* __restrict__ G,
                                                    const float* __restrict__ qg,
                                                    float* __restrict__ Cst,
                                                    float* __restrict__ H,
                                                    ushort_t* __restrict__ H3) {
    int idx = blockIdx.x * 256 + threadIdx.x;
    int b = idx >> 9, j = idx & 511;
    const float* g = G + (size_t)b * GDIM;
    float gi = g[j], gf = g[512 + j], gg = g[1024 + j], go = g[1536 + j];
    float cn;
    if (FIRST)
        cn = sigmoidf_(gi) * tanhf(gg);
    else
        cn = sigmoidf_(gf) * Cst[idx] + sigmoidf_(gi) * tanhf(gg);
    Cst[idx] = cn;
    if (j < 256) {
        float h = qg[(size_t)b * 256 + j] + sigmoidf_(go) * tanhf(cn);
        H[(size_t)b * 256 + j] = h;
        ushort_t hi = f2bf(h);
        ushort_t lo = f2bf(h - bf2f(hi));
        ushort_t* p = H3 + (size_t)b * 768;
        p[j] = hi; p[j + 256] = hi; p[j + 512] = lo;
    }
}

__global__ __launch_bounds__(256) void scores_kernel(const float* __restrict__ H,
                                                     const float* __restrict__ s,
                                                     float* __restrict__ out) {
    int row = blockIdx.x * 4 + (threadIdx.x >> 6);
    int lane = threadIdx.x & 63;
    float4 h = *(const float4*)(H + (size_t)row * 256 + lane * 4);
    float4 sv = *(const float4*)(s + lane * 4);
    float p = h.x * sv.x + h.y * sv.y + h.z * sv.z + h.w * sv.w;
#pragma unroll
    for (int o = 32; o; o >>= 1) p += __shfl_down(p, o);
    if (lane == 0) out[row] = p;
}

__global__ void ws_fail(float* out, int n) {
    int i = blockIdx.x * 256 + threadIdx.x;
    if (i < n) out[i] = -12345.0f;  // workspace-too-small sentinel
}

extern "C" void kernel_launch(void* const* d_in, const int* in_sizes, int n_in,
                              void* d_out, int out_size, void* d_ws, size_t ws_size,
                              hipStream_t stream) {
    const int* qlc = (const int*)d_in[0];
    const float* qld = (const float*)d_in[1];
    const int* qrc = (const int*)d_in[2];
    const float* qrd = (const float*)d_in[3];
    const int* slc = (const int*)d_in[4];
    const float* sld = (const float*)d_in[5];
    const int* src_ = (const int*)d_in[6];
    const float* srd = (const float*)d_in[7];
    const float* emb = (const float*)d_in[8];
    const float* gcn_w = (const float*)d_in[9];
    const float* gcn_b = (const float*)d_in[10];
    const float* w1 = (const float*)d_in[11];
    const float* b1 = (const float*)d_in[12];
    const float* w2 = (const float*)d_in[13];
    const float* b2 = (const float*)d_in[14];
    const float* lna = (const float*)d_in[15];
    const float* lnb = (const float*)d_in[16];
    const float* w_ih = (const float*)d_in[17];
    const float* w_hh = (const float*)d_in[18];
    const float* b_ih = (const float*)d_in[19];
    const float* b_hh = (const float*)d_in[20];
    float* out = (float*)d_out;

    float* ws = (float*)d_ws;
    size_t off = 0;
    auto alloc = [&](size_t n) { float* p = ws + off; off += n; return p; };
    float* gcn_wT = alloc(256 * 128);
    float* qn = alloc((size_t)BATCH * 256);
    float* sn = alloc(FEW * 256);
    float* preq = alloc((size_t)BATCH * 256);
    float* pres = alloc(FEW * 256);
    float* qg = alloc((size_t)BATCH * 256);
    float* sg = alloc(FEW * 256);
    float* H1s = alloc(FEW * 512);
    float* svec = alloc(2048);
    float* bsum = alloc(2048);
    float* sbar = alloc(256);
    float* base = alloc((size_t)BATCH * GDIM);
    float* Gbuf = alloc((size_t)BATCH * GDIM);
    float* Cst = alloc((size_t)BATCH * LHID);
    float* Hst = alloc((size_t)BATCH * 256);
    // bf16 panels (ushort) carved from float workspace (counts are halves)
    ushort_t* qn3   = (ushort_t*)alloc((size_t)BATCH * 768 / 2);
    ushort_t* H1q3  = (ushort_t*)alloc((size_t)BATCH * 1536 / 2);
    ushort_t* qg3   = (ushort_t*)alloc((size_t)BATCH * 768 / 2);
    ushort_t* Hst3  = (ushort_t*)alloc((size_t)BATCH * 768 / 2);
    ushort_t* w13   = (ushort_t*)alloc((size_t)DINNER * 768 / 2);
    ushort_t* w23   = (ushort_t*)alloc((size_t)DMODEL * 1536 / 2);
    ushort_t* wih3  = (ushort_t*)alloc((size_t)GDIM * 768 / 2);
    ushort_t* whh3  = (ushort_t*)alloc((size_t)GDIM * 768 / 2);

    if (ws_size < off * sizeof(float)) {  // loud, distinguishable failure
        ws_fail<<<(out_size + 255) / 256, 256, 0, stream>>>(out, out_size);
        return;
    }

    // one-time weight conversions + gcn transpose
    transpose_gcnw<<<128, 256, 0, stream>>>(gcn_w, gcn_wT);
    convert_w<<<(DINNER * 256 + 255) / 256, 256, 0, stream>>>(w1, 256, w13, 256, DINNER * 256);
    convert_w<<<(DMODEL * 512 + 255) / 256, 256, 0, stream>>>(w2, 512, w23, 512, DMODEL * 512);
    convert_w<<<(GDIM * 256 + 255) / 256, 256, 0, stream>>>(w_ih, 256, wih3, 256, GDIM * 256);
    convert_w<<<(GDIM * 256 + 255) / 256, 256, 0, stream>>>(w_hh, 512, whh3, 256, GDIM * 256);

    nbr_gcn<<<2 * BATCH + 2 * FEW, 256, 0, stream>>>(qlc, qld, qrc, qrd, slc, sld, src_, srd,
                                                     emb, gcn_wT, gcn_b, qn, sn, qn3);

    // support encoder (query): H1 = relu(qn W1^T + b1) -> bf16x3; pre = H1 W2^T + b2 + qn
    gemm_bf3<1, 1, 0, 1><<<dim3(DINNER / 128, BATCH / 64), 256, 0, stream>>>(
        qn3, 768, w13, 768, nullptr, 0, H1q3, DINNER, b1, nullptr, 0, 768);
    gemm_bf3<0, 1, 1, 0><<<dim3(DMODEL / 128, BATCH / 64), 256, 0, stream>>>(
        H1q3, 1536, w23, 1536, preq, 256, nullptr, 0, b2, qn, 256, 1536);
    // support rows (M=5): fp32 path
    small_nt<1, 1, 0><<<(FEW * DINNER + 255) / 256, 256, 0, stream>>>(
        sn, 256, w1, 256, H1s, 512, b1, nullptr, 0, FEW, DINNER, 256);
    small_nt<0, 1, 1><<<(FEW * DMODEL + 255) / 256, 256, 0, stream>>>(
        H1s, 512, w2, 512, pres, 256, b2, sn, 256, FEW, DMODEL, 512);

    ln_kernel<<<BATCH / 4, 256, 0, stream>>>(preq, lna, lnb, qg, qg3, BATCH);
    ln_kernel<<<2, 256, 0, stream>>>(pres, lna, lnb, sg, nullptr, FEW);
    mean5<<<1, 256, 0, stream>>>(sg, sbar);
    svec_bsum<<<GDIM / 4, 256, 0, stream>>>(sbar, w_hh, b_ih, b_hh, svec, bsum);

    // base = qg @ w_ih^T + (b_ih + b_hh)
    gemm_bf3<0, 1, 0, 0><<<dim3(GDIM / 128, BATCH / 64), 256, 0, stream>>>(
        qg3, 768, wih3, 768, base, GDIM, nullptr, 0, bsum, nullptr, 0, 768);

    gates_kernel<1><<<BATCH * LHID / 256, 256, 0, stream>>>(base, qg, Cst, Hst, Hst3);
    for (int s = 2; s <= 4; s++) {
        gemm_bf3<0, 1, 1, 0><<<dim3(GDIM / 128, BATCH / 64), 256, 0, stream>>>(
            Hst3, 768, whh3, 768, Gbuf, GDIM, nullptr, 0, svec, base, GDIM, 768);
        gates_kernel<0><<<BATCH * LHID / 256, 256, 0, stream>>>(Gbuf, qg, Cst, Hst, Hst3);
    }

    scores_kernel<<<BATCH / 4, 256, 0, stream>>>(Hst, sbar, out);
}

// Round 9
// 456.748 us; speedup vs baseline: 1.3415x; 1.3415x over previous
//
#include <hip/hip_runtime.h>

#define NBRS 200
#define BATCH 2048
#define FEW 5
#define DMODEL 256
#define DINNER 512
#define LHID 512
#define GDIM 2048   // 4*LHID
#define EDIM 128
#define LNEPS 1e-3f

typedef unsigned short ushort_t;
typedef short s16x8 __attribute__((ext_vector_type(8)));
typedef float f32x4 __attribute__((ext_vector_type(4)));

__device__ __forceinline__ float sigmoidf_(float x) { return 1.f / (1.f + expf(-x)); }

__device__ __forceinline__ ushort_t f2bf(float f) {  // RNE float->bf16
    union { float f; unsigned u; } v; v.f = f;
    unsigned u = v.u;
    return (ushort_t)((u + 0x7FFFu + ((u >> 16) & 1u)) >> 16);
}
__device__ __forceinline__ float bf2f(ushort_t h) {
    union { unsigned u; float f; } v; v.u = (unsigned)h << 16; return v.f;
}

// async 16B global->LDS (wave-uniform LDS base + lane*16; per-lane global src)
__device__ __forceinline__ void gl_lds16(const ushort_t* g, ushort_t* l) {
    __builtin_amdgcn_global_load_lds(
        (const __attribute__((address_space(1))) unsigned int*)g,
        (__attribute__((address_space(3))) unsigned int*)l, 16, 0, 0);
}

// ---------------------------------------------------------------------------
// Fused gather + sum + GCN matvec + tanh for all 4 connection tables (R7-proven).
// ---------------------------------------------------------------------------
__global__ __launch_bounds__(256) void nbr_gcn(
    const int* __restrict__ qlc, const float* __restrict__ qld,
    const int* __restrict__ qrc, const float* __restrict__ qrd,
    const int* __restrict__ slc, const float* __restrict__ sld,
    const int* __restrict__ src_, const float* __restrict__ srd,
    const float* __restrict__ emb, const float* __restrict__ WT,
    const float* __restrict__ bias, float* __restrict__ qn, float* __restrict__ sn) {
    __shared__ int idx[NBRS * 2];
    __shared__ float red[4][256];
    __shared__ float sS[256];
    __shared__ float part[256];

    int b = blockIdx.x;
    const int* conn; const float* deg; float* outp; int off, row;
    if (b < 2048)      { conn = qlc;  deg = qld; outp = qn; off = 0;   row = b; }
    else if (b < 4096) { conn = qrc;  deg = qrd; outp = qn; off = 128; row = b - 2048; }
    else if (b < 4101) { conn = slc;  deg = sld; outp = sn; off = 0;   row = b - 4096; }
    else               { conn = src_; deg = srd; outp = sn; off = 128; row = b - 4101; }

    int t = threadIdx.x;
    for (int i = t; i < NBRS * 2; i += 256) idx[i] = conn[row * NBRS * 2 + i];
    __syncthreads();

    int g = t >> 6;
    int r = t & 63;
    int sel = r >> 5;
    int d4 = r & 31;
    float4 acc = make_float4(0.f, 0.f, 0.f, 0.f);
#pragma unroll 5
    for (int k = g; k < NBRS; k += 4) {
        int e = idx[k * 2 + sel];
        float4 v = *(const float4*)(emb + (size_t)e * EDIM + d4 * 4);
        acc.x += v.x; acc.y += v.y; acc.z += v.z; acc.w += v.w;
    }
    *(float4*)&red[g][sel * 128 + d4 * 4] = acc;
    __syncthreads();
    sS[t] = red[0][t] + red[1][t] + red[2][t] + red[3][t];
    __syncthreads();

    int d = t & 127;
    int half = t >> 7;
    float a = 0.f;
    const float* w = WT + (size_t)(half * 128) * 128 + d;
    const float* s = sS + half * 128;
#pragma unroll 8
    for (int c = 0; c < 128; ++c) a = fmaf(s[c], w[(size_t)c * 128], a);
    part[t] = a;
    __syncthreads();
    if (t < 128) {
        float v = (part[t] + part[t + 128] + 200.f * bias[t]) / deg[row];
        outp[(size_t)row * 256 + off + t] = tanhf(v);
    }
}

// gcn_w (128,256) -> gcn_wT (256,128)
__global__ void transpose_gcnw(const float* __restrict__ W, float* __restrict__ WT) {
    int i = blockIdx.x * 256 + threadIdx.x;
    int d = i >> 8, c = i & 255;
    WT[c * 128 + d] = W[i];
}

// Weight fp32 (N rows, K cols used, row stride src_ld) -> N x 3K bf16 [hi, lo, hi]
__global__ __launch_bounds__(256) void convert_w(const float* __restrict__ W, int src_ld,
                                                 ushort_t* __restrict__ W3, int K, int total) {
    int i = blockIdx.x * 256 + threadIdx.x;
    if (i >= total) return;
    int n = i / K, k = i % K;
    float w = W[(size_t)n * src_ld + k];
    ushort_t hi = f2bf(w);
    ushort_t lo = f2bf(w - bf2f(hi));
    ushort_t* p = W3 + (size_t)n * 3 * K;
    p[k] = hi; p[K + k] = lo; p[2 * K + k] = hi;
}

// ---------------------------------------------------------------------------
// bf16 MFMA NT GEMM v2 over x3-split panels: C = A·B^T + bias (+addm), fp32 out.
// A: M x K' bf16 row-major, B: N x K' bf16 row-major. M%64==0, N%128==0, K'%64==0.
// Tile 64x128, BK=64, 256 thr = 4 waves (2Mx2N), wave 32x64 (2x4 frags 16x16x32).
// 2-phase async pipeline (catalog T3-minimum): double-buffered LDS filled by
// global_load_lds w/ PRE-SWIZZLED global source (m173) -> linear DMA dest lands
// XOR-swizzled; ONE barrier per K-step; loads issued before MFMA phase.
// LDS[row][slot] = global[row][slot ^ (row&7)]; reads use slot s^(row&7).
// ---------------------------------------------------------------------------
template <int BIAS, int ADD>
__global__ __launch_bounds__(256) void gemm_bf3(
    const ushort_t* __restrict__ A, int lda,
    const ushort_t* __restrict__ B, int ldb,
    float* __restrict__ Cf, int ldc,
    const float* __restrict__ bias,
    const float* __restrict__ addm, int ldadd, int K) {
    __shared__ ushort_t As[2][64 * 64];
    __shared__ ushort_t Bs[2][128 * 64];
    const int tid = threadIdx.x;
    const int m0 = blockIdx.y * 64;
    const int n0 = blockIdx.x * 128;
    const int w4 = tid >> 6, lane = tid & 63;
    const int wm = w4 >> 1, wn = w4 & 1;
    const int fr = lane & 15, fq = lane >> 4;

    f32x4 zero = {0.f, 0.f, 0.f, 0.f};
    f32x4 acc[2][4];
#pragma unroll
    for (int i = 0; i < 2; i++)
#pragma unroll
        for (int j = 0; j < 4; j++) acc[i][j] = zero;

    // 24 segments of 8 rows x 128B: A = segs 0..7, B = segs 8..23; 6 per wave.
    const int lrow = lane >> 3;        // row within segment
    const int lslot = lane & 7;        // 16B slot within row (DMA dest = linear)
    auto stage = [&](int buf, int k0) {
#pragma unroll
        for (int s6 = 0; s6 < 6; ++s6) {
            int s = w4 * 6 + s6;
            if (s < 8) {
                int row = s * 8 + lrow;
                const ushort_t* src = A + (size_t)(m0 + row) * lda + k0 + ((lslot ^ (row & 7)) << 3);
                gl_lds16(src, &As[buf][s * 8 * 64]);
            } else {
                int row = (s - 8) * 8 + lrow;
                const ushort_t* src = B + (size_t)(n0 + row) * ldb + k0 + ((lslot ^ (row & 7)) << 3);
                gl_lds16(src, &Bs[buf][(s - 8) * 8 * 64]);
            }
        }
    };

    const int nt = K / 64;
    stage(0, 0);
    __syncthreads();  // drains vmcnt -> buf0 ready
    int cur = 0;
    for (int kt = 0; kt < nt; ++kt) {
        if (kt + 1 < nt) stage(cur ^ 1, (kt + 1) * 64);  // async, hides under MFMA
#pragma unroll
        for (int ks = 0; ks < 2; ++ks) {
            s16x8 av[2], bv[4];
#pragma unroll
            for (int fm = 0; fm < 2; ++fm) {
                int rw = wm * 32 + fm * 16 + fr;
                int s16 = ks * 4 + fq;
                av[fm] = *(const s16x8*)&As[cur][rw * 64 + ((s16 ^ (rw & 7)) << 3)];
            }
#pragma unroll
            for (int fn = 0; fn < 4; ++fn) {
                int rw = wn * 64 + fn * 16 + fr;
                int s16 = ks * 4 + fq;
                bv[fn] = *(const s16x8*)&Bs[cur][rw * 64 + ((s16 ^ (rw & 7)) << 3)];
            }
#pragma unroll
            for (int fm = 0; fm < 2; ++fm)
#pragma unroll
                for (int fn = 0; fn < 4; ++fn)
                    acc[fm][fn] = __builtin_amdgcn_mfma_f32_16x16x32_bf16(
                        av[fm], bv[fn], acc[fm][fn], 0, 0, 0);
        }
        if (kt + 1 < nt) {  // one barrier per K-step: drains stage, releases buf
            __syncthreads();
            cur ^= 1;
        }
    }

#pragma unroll
    for (int fm = 0; fm < 2; ++fm)
#pragma unroll
        for (int fn = 0; fn < 4; ++fn)
#pragma unroll
            for (int r = 0; r < 4; ++r) {
                int gm = m0 + wm * 32 + fm * 16 + fq * 4 + r;
                int gn = n0 + wn * 64 + fn * 16 + fr;
                float v = acc[fm][fn][r];
                if (BIAS) v += bias[gn];
                if (ADD) v += addm[(size_t)gm * ldadd + gn];
                Cf[(size_t)gm * ldc + gn] = v;
            }
}

// ---------------------------------------------------------------------------
// fp32 NT GEMM (R7-proven): single-buffered LDS + register prefetch.
// ---------------------------------------------------------------------------
template <int RELU, int BIAS, int ADD>
__global__ __launch_bounds__(256) void gemm64(const float* __restrict__ A, int lda,
                                              const float* __restrict__ B, int ldb,
                                              float* __restrict__ C, int ldc,
                                              const float* __restrict__ bias,
                                              const float* __restrict__ addm, int ldadd,
                                              int K) {
    constexpr int BK = 32;
    __shared__ float As[BK][65];
    __shared__ float Bs[BK][65];
    const int tid = threadIdx.x;
    const int m0 = blockIdx.y * 64;
    const int n0 = blockIdx.x * 64;
    const int tn = tid & 15;
    const int tm = tid >> 4;
    const int r = tid >> 2;
    const int c8 = (tid & 3) * 8;

    float acc[4][4];
#pragma unroll
    for (int i = 0; i < 4; i++)
#pragma unroll
        for (int j = 0; j < 4; j++) acc[i][j] = 0.f;

    const float* pa = A + (size_t)(m0 + r) * lda + c8;
    const float* pb = B + (size_t)(n0 + r) * ldb + c8;
    float4 a0 = *(const float4*)pa;
    float4 a1 = *(const float4*)(pa + 4);
    float4 b0 = *(const float4*)pb;
    float4 b1 = *(const float4*)(pb + 4);

    const int nt = K / BK;
    for (int t = 0; t < nt; ++t) {
        if (t) __syncthreads();
        As[c8 + 0][r] = a0.x; As[c8 + 1][r] = a0.y; As[c8 + 2][r] = a0.z; As[c8 + 3][r] = a0.w;
        As[c8 + 4][r] = a1.x; As[c8 + 5][r] = a1.y; As[c8 + 6][r] = a1.z; As[c8 + 7][r] = a1.w;
        Bs[c8 + 0][r] = b0.x; Bs[c8 + 1][r] = b0.y; Bs[c8 + 2][r] = b0.z; Bs[c8 + 3][r] = b0.w;
        Bs[c8 + 4][r] = b1.x; Bs[c8 + 5][r] = b1.y; Bs[c8 + 6][r] = b1.z; Bs[c8 + 7][r] = b1.w;
        __syncthreads();
        if (t + 1 < nt) {
            const float* qa = pa + (t + 1) * BK;
            const float* qb = pb + (t + 1) * BK;
            a0 = *(const float4*)qa;
            a1 = *(const float4*)(qa + 4);
            b0 = *(const float4*)qb;
            b1 = *(const float4*)(qb + 4);
        }
#pragma unroll
        for (int kk = 0; kk < BK; ++kk) {
            const float4 av = *(const float4*)&As[kk][tm * 4];
            const float4 bv = *(const float4*)&Bs[kk][tn * 4];
            float ar[4] = {av.x, av.y, av.z, av.w};
            float br[4] = {bv.x, bv.y, bv.z, bv.w};
#pragma unroll
            for (int i = 0; i < 4; i++)
#pragma unroll
                for (int j = 0; j < 4; j++) acc[i][j] = fmaf(ar[i], br[j], acc[i][j]);
        }
    }

#pragma unroll
    for (int i = 0; i < 4; ++i) {
        int gm = m0 + tm * 4 + i;
        int gn = n0 + tn * 4;
        float4 v = make_float4(acc[i][0], acc[i][1], acc[i][2], acc[i][3]);
        if (BIAS) {
            const float4 bv = *(const float4*)&bias[gn];
            v.x += bv.x; v.y += bv.y; v.z += bv.z; v.w += bv.w;
        }
        if (ADD) {
            const float4 av = *(const float4*)&addm[(size_t)gm * ldadd + gn];
            v.x += av.x; v.y += av.y; v.z += av.z; v.w += av.w;
        }
        if (RELU) {
            v.x = fmaxf(v.x, 0.f); v.y = fmaxf(v.y, 0.f);
            v.z = fmaxf(v.z, 0.f); v.w = fmaxf(v.w, 0.f);
        }
        *(float4*)&C[(size_t)gm * ldc + gn] = v;
    }
}

// Tiny-M GEMM (M=5 support rows): one thread per output. fp32.
template <int RELU, int BIAS, int ADD>
__global__ __launch_bounds__(256) void small_nt(const float* __restrict__ A, int lda,
                                                const float* __restrict__ B, int ldb,
                                                float* __restrict__ C, int ldc,
                                                const float* __restrict__ bias,
                                                const float* __restrict__ addm, int ldadd,
                                                int M, int N, int K) {
    int o = blockIdx.x * 256 + threadIdx.x;
    if (o >= M * N) return;
    int m = o / N, n = o % N;
    const float4* a4 = (const float4*)(A + (size_t)m * lda);
    const float4* b4 = (const float4*)(B + (size_t)n * ldb);
    float s = 0.f;
#pragma unroll 8
    for (int k = 0; k < K / 4; ++k) {
        float4 x = a4[k], y = b4[k];
        s += x.x * y.x + x.y * y.y + x.z * y.z + x.w * y.w;
    }
    if (BIAS) s += bias[n];
    if (ADD) s += addm[(size_t)m * ldadd + n];
    if (RELU) s = fmaxf(s, 0.f);
    C[(size_t)m * ldc + n] = s;
}

// LayerNorm (ddof=1), one wave per 256-elem row; optional bf16x3 panel out.
__global__ __launch_bounds__(256) void ln_kernel(const float* __restrict__ X,
                                                 const float* __restrict__ la,
                                                 const float* __restrict__ lb,
                                                 float* __restrict__ Y,
                                                 ushort_t* __restrict__ Y3, int n) {
    int row = blockIdx.x * 4 + (threadIdx.x >> 6);
    int lane = threadIdx.x & 63;
    if (row >= n) return;
    float4 x = *(const float4*)(X + (size_t)row * 256 + lane * 4);
    float s = x.x + x.y + x.z + x.w;
#pragma unroll
    for (int o = 32; o; o >>= 1) s += __shfl_xor(s, o);
    float mu = s * (1.f / 256.f);
    float d0 = x.x - mu, d1 = x.y - mu, d2 = x.z - mu, d3 = x.w - mu;
    float q = d0 * d0 + d1 * d1 + d2 * d2 + d3 * d3;
#pragma unroll
    for (int o = 32; o; o >>= 1) q += __shfl_xor(q, o);
    float sigma = sqrtf(q * (1.f / 255.f));
    float inv = 1.f / (sigma + LNEPS);
    float4 a = *(const float4*)(la + lane * 4);
    float4 b = *(const float4*)(lb + lane * 4);
    float4 y = make_float4(d0 * inv * a.x + b.x, d1 * inv * a.y + b.y,
                           d2 * inv * a.z + b.z, d3 * inv * a.w + b.w);
    *(float4*)(Y + (size_t)row * 256 + lane * 4) = y;
    if (Y3) {
        ushort_t* p = Y3 + (size_t)row * 768;
        float vv[4] = {y.x, y.y, y.z, y.w};
#pragma unroll
        for (int c = 0; c < 4; ++c) {
            int col = lane * 4 + c;
            ushort_t hi = f2bf(vv[c]);
            p[col] = hi; p[col + 256] = hi; p[col + 512] = f2bf(vv[c] - bf2f(hi));
        }
    }
}

__global__ void mean5(const float* __restrict__ sg, float* __restrict__ s) {
    int d = threadIdx.x;
    float v = 0.f;
#pragma unroll
    for (int r = 0; r < FEW; r++) v += sg[r * 256 + d];
    s[d] = v * (1.f / FEW);
}

__global__ __launch_bounds__(256) void svec_bsum(const float* __restrict__ s,
                                                 const float* __restrict__ w_hh,
                                                 const float* __restrict__ b_ih,
                                                 const float* __restrict__ b_hh,
                                                 float* __restrict__ svec,
                                                 float* __restrict__ bsum) {
    int j = blockIdx.x * 4 + (threadIdx.x >> 6);
    int lane = threadIdx.x & 63;
    const float* w = w_hh + (size_t)j * LHID + 256;
    float4 v = ((const float4*)w)[lane];
    float4 sv = ((const float4*)s)[lane];
    float p = v.x * sv.x + v.y * sv.y + v.z * sv.z + v.w * sv.w;
#pragma unroll
    for (int o = 32; o; o >>= 1) p += __shfl_down(p, o);
    if (lane == 0) {
        svec[j] = p;
        bsum[j] = b_ih[j] + b_hh[j];
    }
}

// LSTM gates; H fp32 + Hst3 bf16x3 panel for the next step GEMM.
template <int FIRST>
__global__ __launch_bounds__(256) void gates_kernel(const float* __restrict__ G,
                                                    const float* __restrict__ qg,
                                                    float* __restrict__ Cst,
                                                    float* __restrict__ H,
                                                    ushort_t* __restrict__ H3) {
    int idx = blockIdx.x * 256 + threadIdx.x;
    int b = idx >> 9, j = idx & 511;
    const float* g = G + (size_t)b * GDIM;
    float gi = g[j], gf = g[512 + j], gg = g[1024 + j], go = g[1536 + j];
    float cn;
    if (FIRST)
        cn = sigmoidf_(gi) * tanhf(gg);
    else
        cn = sigmoidf_(gf) * Cst[idx] + sigmoidf_(gi) * tanhf(gg);
    Cst[idx] = cn;
    if (j < 256) {
        float h = qg[(size_t)b * 256 + j] + sigmoidf_(go) * tanhf(cn);
        H[(size_t)b * 256 + j] = h;
        ushort_t hi = f2bf(h);
        ushort_t lo = f2bf(h - bf2f(hi));
        ushort_t* p = H3 + (size_t)b * 768;
        p[j] = hi; p[j + 256] = hi; p[j + 512] = lo;
    }
}

__global__ __launch_bounds__(256) void scores_kernel(const float* __restrict__ H,
                                                     const float* __restrict__ s,
                                                     float* __restrict__ out) {
    int row = blockIdx.x * 4 + (threadIdx.x >> 6);
    int lane = threadIdx.x & 63;
    float4 h = *(const float4*)(H + (size_t)row * 256 + lane * 4);
    float4 sv = *(const float4*)(s + lane * 4);
    float p = h.x * sv.x + h.y * sv.y + h.z * sv.z + h.w * sv.w;
#pragma unroll
    for (int o = 32; o; o >>= 1) p += __shfl_down(p, o);
    if (lane == 0) out[row] = p;
}

__global__ void ws_fail(float* out, int n) {
    int i = blockIdx.x * 256 + threadIdx.x;
    if (i < n) out[i] = -12345.0f;
}

extern "C" void kernel_launch(void* const* d_in, const int* in_sizes, int n_in,
                              void* d_out, int out_size, void* d_ws, size_t ws_size,
                              hipStream_t stream) {
    const int* qlc = (const int*)d_in[0];
    const float* qld = (const float*)d_in[1];
    const int* qrc = (const int*)d_in[2];
    const float* qrd = (const float*)d_in[3];
    const int* slc = (const int*)d_in[4];
    const float* sld = (const float*)d_in[5];
    const int* src_ = (const int*)d_in[6];
    const float* srd = (const float*)d_in[7];
    const float* emb = (const float*)d_in[8];
    const float* gcn_w = (const float*)d_in[9];
    const float* gcn_b = (const float*)d_in[10];
    const float* w1 = (const float*)d_in[11];
    const float* b1 = (const float*)d_in[12];
    const float* w2 = (const float*)d_in[13];
    const float* b2 = (const float*)d_in[14];
    const float* lna = (const float*)d_in[15];
    const float* lnb = (const float*)d_in[16];
    const float* w_ih = (const float*)d_in[17];
    const float* w_hh = (const float*)d_in[18];
    const float* b_ih = (const float*)d_in[19];
    const float* b_hh = (const float*)d_in[20];
    float* out = (float*)d_out;

    float* ws = (float*)d_ws;
    size_t off = 0;
    auto alloc = [&](size_t n) { float* p = ws + off; off += n; return p; };
    float* gcn_wT = alloc(256 * 128);
    float* qn = alloc((size_t)BATCH * 256);
    float* sn = alloc(FEW * 256);
    float* H1q = alloc((size_t)BATCH * 512);
    float* H1s = alloc(FEW * 512);
    float* preq = alloc((size_t)BATCH * 256);
    float* pres = alloc(FEW * 256);
    float* qg = alloc((size_t)BATCH * 256);
    float* sg = alloc(FEW * 256);
    float* svec = alloc(2048);
    float* bsum = alloc(2048);
    float* sbar = alloc(256);
    float* base = alloc((size_t)BATCH * GDIM);
    float* Gbuf = alloc((size_t)BATCH * GDIM);
    float* Cst = alloc((size_t)BATCH * LHID);
    float* Hst = alloc((size_t)BATCH * 256);
    // bf16 panels (ushort counts halved into float slots)
    ushort_t* qg3  = (ushort_t*)alloc((size_t)BATCH * 768 / 2);
    ushort_t* Hst3 = (ushort_t*)alloc((size_t)BATCH * 768 / 2);
    ushort_t* wih3 = (ushort_t*)alloc((size_t)GDIM * 768 / 2);
    ushort_t* whh3 = (ushort_t*)alloc((size_t)GDIM * 768 / 2);

    if (ws_size < off * sizeof(float)) {
        ws_fail<<<(out_size + 255) / 256, 256, 0, stream>>>(out, out_size);
        return;
    }

    transpose_gcnw<<<128, 256, 0, stream>>>(gcn_w, gcn_wT);
    convert_w<<<(GDIM * 256 + 255) / 256, 256, 0, stream>>>(w_ih, 256, wih3, 256, GDIM * 256);
    convert_w<<<(GDIM * 256 + 255) / 256, 256, 0, stream>>>(w_hh, 512, whh3, 256, GDIM * 256);

    nbr_gcn<<<2 * BATCH + 2 * FEW, 256, 0, stream>>>(qlc, qld, qrc, qrd, slc, sld, src_, srd,
                                                     emb, gcn_wT, gcn_b, qn, sn);

    // support encoder: fp32 (R7-proven). H1 = relu(X W1^T + b1); pre = H1 W2^T + b2 + X; LN
    gemm64<1, 1, 0><<<dim3(DINNER / 64, BATCH / 64), 256, 0, stream>>>(
        qn, 256, w1, 256, H1q, 512, b1, nullptr, 0, 256);
    gemm64<0, 1, 1><<<dim3(DMODEL / 64, BATCH / 64), 256, 0, stream>>>(
        H1q, 512, w2, 512, preq, 256, b2, qn, 256, 512);
    small_nt<1, 1, 0><<<(FEW * DINNER + 255) / 256, 256, 0, stream>>>(
        sn, 256, w1, 256, H1s, 512, b1, nullptr, 0, FEW, DINNER, 256);
    small_nt<0, 1, 1><<<(FEW * DMODEL + 255) / 256, 256, 0, stream>>>(
        H1s, 512, w2, 512, pres, 256, b2, sn, 256, FEW, DMODEL, 512);

    ln_kernel<<<BATCH / 4, 256, 0, stream>>>(preq, lna, lnb, qg, qg3, BATCH);
    ln_kernel<<<2, 256, 0, stream>>>(pres, lna, lnb, sg, nullptr, FEW);
    mean5<<<1, 256, 0, stream>>>(sg, sbar);
    svec_bsum<<<GDIM / 4, 256, 0, stream>>>(sbar, w_hh, b_ih, b_hh, svec, bsum);

    // LSTM GEMMs on MFMA: base = qg @ w_ih^T + (b_ih + b_hh)
    gemm_bf3<1, 0><<<dim3(GDIM / 128, BATCH / 64), 256, 0, stream>>>(
        qg3, 768, wih3, 768, base, GDIM, bsum, nullptr, 0, 768);

    gates_kernel<1><<<BATCH * LHID / 256, 256, 0, stream>>>(base, qg, Cst, Hst, Hst3);
    for (int s = 2; s <= 4; s++) {
        gemm_bf3<1, 1><<<dim3(GDIM / 128, BATCH / 64), 256, 0, stream>>>(
            Hst3, 768, whh3, 768, Gbuf, GDIM, svec, base, GDIM, 768);
        gates_kernel<0><<<BATCH * LHID / 256, 256, 0, stream>>>(Gbuf, qg, Cst, Hst, Hst3);
    }

    scores_kernel<<<BATCH / 4, 256, 0, stream>>>(Hst, sbar, out);
}